// Round 3
// baseline (305.780 us; speedup 1.0000x reference)
//
#include <hip/hip_runtime.h>
#include <cstdint>
#include <cstddef>

#define TPB 256

namespace {

constexpr int B_SZ = 2;
constexpr int C    = 128;
constexpr int HALF = 64;
constexpr int L    = 4096;   // 64*64
constexpr int N    = 16;
constexpr int HH   = 64;
constexpr int WW   = 64;
// padded x_dbl row: [dt 0..RT) | pad | B 16..32 | C 32..48  (192B = 64B-aligned B/C)
constexpr int ROW  = 48;

// fast-math (hardware v_exp_f32/v_log_f32); ~1e-7 rel err, fine at 9.7e-2 threshold
__device__ __forceinline__ float softplusf(float x) {
  return fmaxf(x, 0.f) + __logf(1.f + __expf(-fabsf(x)));
}
__device__ __forceinline__ float sigm(float x) { return 1.f / (1.f + __expf(-x)); }

__device__ __forceinline__ unsigned long long unc_key(float u, int i) {
  unsigned m = __float_as_uint(u);
  m = (m & 0x80000000u) ? ~m : (m | 0x80000000u);   // monotone ascending map
  return ((unsigned long long)(~m) << 32) | (unsigned)i;  // ascending = descending unc, stable
}

// ---------- per-pixel channel LN over 128 channels (CHW): Y = w*(x-m)*r + b ----------
__global__ void k_pixln(const float* __restrict__ X, const float* __restrict__ w,
                        const float* __restrict__ bchan, float* __restrict__ Y) {
  const int px = threadIdx.x & 31;
  const int g  = threadIdx.x >> 5;
  const int p  = blockIdx.x * 32 + px;
  const int b  = p / L, l = p % L;
  const float* Xp = X + (size_t)b * C * L + l;
  float v[16];
  float s = 0.f, s2 = 0.f;
#pragma unroll
  for (int j = 0; j < 16; ++j) {
    float t = Xp[(size_t)(g * 16 + j) * L];
    v[j] = t; s += t; s2 += t * t;
  }
  __shared__ float red[2][8][32];
  red[0][g][px] = s; red[1][g][px] = s2;
  __syncthreads();
  float st = 0.f, qt = 0.f;
#pragma unroll
  for (int k = 0; k < 8; ++k) { st += red[0][k][px]; qt += red[1][k][px]; }
  const float m = st * (1.f / C);
  const float r = rsqrtf(qt * (1.f / C) - m * m + 1e-6f);
  float* Yp = Y + (size_t)b * C * L + l;
#pragma unroll
  for (int j = 0; j < 16; ++j) {
    int c = g * 16 + j;
    Yp[(size_t)c * L] = w[c] * (v[j] - m) * r + bchan[c];
  }
}

// ---------- cat-LN: ycat = LN(concat(yf, rev(yb))) ----------
__global__ void k_lncat(const float* __restrict__ yf, const float* __restrict__ yb,
                        const float* __restrict__ w, const float* __restrict__ bchan,
                        float* __restrict__ Y) {
  const int px = threadIdx.x & 31;
  const int g  = threadIdx.x >> 5;
  const int p  = blockIdx.x * 32 + px;
  const int b  = p / L, l = p % L;
  float v[16];
  float s = 0.f, s2 = 0.f;
#pragma unroll
  for (int j = 0; j < 16; ++j) {
    int c = g * 16 + j;
    float t = (c < 64) ? yf[((size_t)b * HALF + c) * L + l]
                       : yb[((size_t)b * HALF + (c - 64)) * L + (L - 1 - l)];
    v[j] = t; s += t; s2 += t * t;
  }
  __shared__ float red[2][8][32];
  red[0][g][px] = s; red[1][g][px] = s2;
  __syncthreads();
  float st = 0.f, qt = 0.f;
#pragma unroll
  for (int k = 0; k < 8; ++k) { st += red[0][k][px]; qt += red[1][k][px]; }
  const float m = st * (1.f / C);
  const float r = rsqrtf(qt * (1.f / C) - m * m + 1e-6f);
  float* Yp = Y + (size_t)b * C * L + l;
#pragma unroll
  for (int j = 0; j < 16; ++j) {
    int c = g * 16 + j;
    Yp[(size_t)c * L] = w[c] * (v[j] - m) * r + bchan[c];
  }
}

// ---------- inproj: pure 1x1 conv, weights via uniform (scalar) loads ----------
__global__ void k_conv_in(const float* __restrict__ X,
                          const float* __restrict__ W, const float* __restrict__ bias,
                          float* __restrict__ Y,
                          float* __restrict__ st1s, float* __restrict__ st1q) {
  constexpr int O_PB = 8;
  const int o0 = blockIdx.y * O_PB;
  const int b  = blockIdx.z;
  const int l = blockIdx.x * TPB + threadIdx.x;
  const float* X0 = X + (size_t)b * C * L + l;
  const float* Wp = W + (size_t)o0 * 128;     // wave-uniform -> s_load
  float acc[O_PB];
#pragma unroll
  for (int k = 0; k < O_PB; ++k) acc[k] = bias[o0 + k];
#pragma unroll 8
  for (int i = 0; i < 128; ++i) {
    float xv = X0[(size_t)i * L];
#pragma unroll
    for (int k = 0; k < O_PB; ++k) acc[k] += Wp[k * 128 + i] * xv;
  }
#pragma unroll
  for (int k = 0; k < O_PB; ++k)
    Y[((size_t)b * 256 + o0 + k) * L + l] = acc[k];
  if (o0 < 128) {
    float ss = 0.f, qq = 0.f;
#pragma unroll
    for (int k = 0; k < O_PB; ++k) { ss += acc[k]; qq += acc[k] * acc[k]; }
    atomicAdd(&st1s[b * L + l], ss);
    atomicAdd(&st1q[b * L + l], qq);
  }
}

// ---------- depthwise 3x3 + SiLU via LDS halo tile; mode0 LN (from sum/sumsq) ----------
__global__ void k_dwconv_t(const float* __restrict__ xp,
                           const float* __restrict__ st1s, const float* __restrict__ st1q,
                           const float* __restrict__ lnw, const float* __restrict__ lnb,
                           const float* __restrict__ Wm, const float* __restrict__ bm,
                           const float* __restrict__ Wr, const float* __restrict__ br,
                           float* __restrict__ xm, float* __restrict__ xr) {
  const int c = blockIdx.y;
  const int z = blockIdx.z;
  const int b = z & 1, mode = z >> 1;     // 0: mamba (LN), 1: res
  const int h0 = blockIdx.x * 4;
  __shared__ float T[6][66];
  const float* Xc = xp + ((size_t)b * 2 * C + (mode ? C + c : c)) * L;
  const float lw = mode ? 0.f : lnw[c];
  const float lb2 = mode ? 0.f : lnb[c];
  for (int t = threadIdx.x; t < 6 * 66; t += TPB) {
    int r = t / 66, cc = t % 66 - 1;
    int hh = h0 - 1 + r;
    float v = 0.f;
    if (hh >= 0 && hh < HH && cc >= 0 && cc < WW) {
      int li = hh * WW + cc;
      v = Xc[li];
      if (mode == 0) {
        float sv = st1s[b * L + li], qv = st1q[b * L + li];
        float m = sv * (1.f / 128.f);
        float rr = rsqrtf(qv * (1.f / 128.f) - m * m + 1e-6f);
        v = (v - m) * rr * lw + lb2;
      }
    }
    T[r][t % 66] = v;
  }
  __syncthreads();
  const int hl = threadIdx.x >> 6, w = threadIdx.x & 63;
  const float* W9 = (mode ? Wr : Wm) + c * 9;
  float acc = mode ? br[c] : bm[c];
#pragma unroll
  for (int kh = 0; kh < 3; ++kh)
#pragma unroll
    for (int kw = 0; kw < 3; ++kw)
      acc += T[hl + kh][w + kw] * W9[kh * 3 + kw];
  const int l = (h0 + hl) * WW + w;
  float* Yp = mode ? xr : xm;
  Yp[((size_t)b * C + c) * L + l] = acc * sigm(acc);
}

// ---------- uncertainty per pixel (kept byte-identical: preserves sort dice) ----------
__global__ void k_unc(const float* __restrict__ xm, float* __restrict__ unc) {
  const int lp = threadIdx.x & 63;
  const int wv = threadIdx.x >> 6;
  const int p  = blockIdx.x * 64 + lp;
  const int b = p / L, l = p % L;
  const float* Xp = xm + (size_t)b * C * L + l;
  float s = 0.f;
#pragma unroll 8
  for (int i = 0; i < 32; ++i) s += Xp[(size_t)(wv * 32 + i) * L];
  __shared__ float r1[4][64];
  r1[wv][lp] = s;
  __syncthreads();
  if (wv == 0) {
    float st = r1[0][lp] + r1[1][lp] + r1[2][lp] + r1[3][lp];
    float sg = sigm(st / C);
    unc[p] = -(sg * __logf(sg + 1e-6f));
  }
}

// ---------- stable rank of descending unc: rank_i = #{j: ckey_j < ckey_i} ----------
__global__ void k_rank(const float* __restrict__ unc, int* __restrict__ rankbuf) {
  constexpr int JC = 512;
  __shared__ unsigned long long K[JC];
  const int b  = blockIdx.z;
  const int j0 = blockIdx.y * JC;
  const int i  = blockIdx.x * TPB + threadIdx.x;
  for (int t = threadIdx.x; t < JC; t += TPB)
    K[t] = unc_key(unc[b * L + j0 + t], j0 + t);
  __syncthreads();
  const unsigned long long my = unc_key(unc[b * L + i], i);
  int cnt = 0;
#pragma unroll 8
  for (int j = 0; j < JC; ++j) cnt += (K[j] < my) ? 1 : 0;
  atomicAdd(&rankbuf[b * L + i], cnt);
}

// ---------- invert rank -> idx: idx[rank[l]] = l ----------
__global__ void k_invidx(const int* __restrict__ rankbuf, int* __restrict__ idx) {
  const int t = blockIdx.x * TPB + threadIdx.x;   // 8192
  const int b = t / L, l = t % L;
  idx[b * L + rankbuf[b * L + l]] = l;
}

// ---------- gather: xs[b,c,r] = xm[b,c,idx[r]] (coalesced stores, L2-hit gathers) ----------
__global__ void k_gather(const float* __restrict__ xm, const int* __restrict__ idx,
                         float* __restrict__ xs) {
  const int b  = blockIdx.z;
  const int c0 = blockIdx.y * 8;
  const int r  = blockIdx.x * TPB + threadIdx.x;
  const int li = idx[b * L + r];
  const float* Xb = xm + (size_t)b * C * L;
  float* Yb = xs + (size_t)b * C * L;
#pragma unroll
  for (int j = 0; j < 8; ++j) {
    int c = c0 + j;
    Yb[(size_t)c * L + r] = Xb[(size_t)c * L + li];
  }
}

// ---------- merged x-projection conv: z 0..3 = f/b dirs, z 4..5 = u (reads xs) ----------
// writes into padded ROW=48 layout (dt at 0..RT, B at 16..32, C at 32..48)
__global__ void k_convx_all(const float* __restrict__ xm, const float* __restrict__ xs,
                            const float* __restrict__ Wf, const float* __restrict__ bf,
                            const float* __restrict__ Wb, const float* __restrict__ bb,
                            const float* __restrict__ Wu, const float* __restrict__ bu,
                            float* __restrict__ XDF, float* __restrict__ XDU) {
  const int z = blockIdx.z;
  const bool isU = z >= 4;
  const int I = isU ? 128 : 64;
  const int O = isU ? 40 : 36;
  const int RT = isU ? 8 : 4;
  const int o0 = blockIdx.y * 4;
  if (o0 >= O) return;                 // block-uniform
  int b, dir;
  const float *W, *bi;
  if (!isU) { dir = z >> 1; b = z & 1; W = dir ? Wb : Wf; bi = dir ? bb : bf; }
  else      { dir = 0; b = z - 4; W = Wu; bi = bu; }
  const float* Wp = W + (size_t)o0 * I;      // wave-uniform -> s_load
  const int l = blockIdx.x * TPB + threadIdx.x;
  const int ls = isU ? l : (dir ? (L - 1 - l) : l);
  const float* Xb = isU ? (xs + (size_t)b * C * L)
                        : (xm + ((size_t)b * C + dir * HALF) * L);
  float acc[4];
#pragma unroll
  for (int k = 0; k < 4; ++k) acc[k] = bi[o0 + k];
#pragma unroll 8
  for (int i = 0; i < I; ++i) {
    float xv = Xb[(size_t)i * L + ls];
#pragma unroll
    for (int k = 0; k < 4; ++k) acc[k] += Wp[(size_t)k * I + i] * xv;
  }
  const int slot0 = (o0 < RT) ? o0 : o0 + (16 - RT);
  float* yp = isU ? (XDU + ((size_t)b * L + l) * ROW + slot0)
                  : (XDF + ((size_t)z * L + l) * ROW + slot0);
#pragma unroll
  for (int k = 0; k < 4; ++k) yp[k] = acc[k];
}

// ---------- merged fused selective scan (512 blocks); U writes UNSORTED via idx ----------
__global__ __launch_bounds__(1024) void
k_scan_all(const float* __restrict__ xdblF, const float* __restrict__ xdblU,
           const float* __restrict__ dtf_w, const float* __restrict__ dtf_b,
           const float* __restrict__ dtb_w, const float* __restrict__ dtb_b,
           const float* __restrict__ dtu_w, const float* __restrict__ dtu_b,
           const float* __restrict__ xm, const float* __restrict__ xs,
           const int* __restrict__ idx,
           const float* __restrict__ Alog_f, const float* __restrict__ Alog_b,
           const float* __restrict__ Alog_u,
           const float* __restrict__ D_f, const float* __restrict__ D_b,
           const float* __restrict__ D_u,
           float* __restrict__ yf, float* __restrict__ yb, float* __restrict__ yu) {
  const int blk = blockIdx.x;
  const int tid = threadIdx.x;
  const bool isU = blk >= 256;
  int CsT, RT, c, b, dir;
  const float *Wdt, *bdt, *Alog, *Dv, *xdbl, *Ub;
  const int* idxb = nullptr;
  float* Y;
  if (!isU) {
    CsT = 64; RT = 4;
    int zb = blk >> 6; c = blk & 63; dir = zb >> 1; b = zb & 1;
    Wdt = dir ? dtb_w : dtf_w; bdt = dir ? dtb_b : dtf_b;
    Alog = dir ? Alog_b : Alog_f; Dv = dir ? D_b : D_f;
    xdbl = xdblF + (size_t)zb * L * ROW;
    Ub = xm + ((size_t)b * C + dir * HALF + c) * L;
    Y = (dir ? yb : yf) + ((size_t)b * HALF + c) * L;
  } else {
    CsT = 128; RT = 8;
    int blk2 = blk - 256; b = blk2 >> 7; c = blk2 & 127; dir = 0;
    Wdt = dtu_w; bdt = dtu_b; Alog = Alog_u; Dv = D_u;
    xdbl = xdblU + (size_t)b * L * ROW;
    Ub = xs + ((size_t)b * C + c) * L;
    idxb = idx + b * L;
    Y = yu + ((size_t)b * C + c) * L;
  }
  __shared__ float sW[1024];            // transposed: sW[r*CsT + csrc]
  __shared__ float sb2[128];
  __shared__ float4 dtL4[64 * 17];      // d  (row = 17 float4 = 68 floats, 16B-aligned)
  __shared__ float4 uL4[64 * 17];       // u
  __shared__ float sA[N][65], sH[N][65];
  for (int t = tid; t < CsT * RT; t += 1024) {
    int csrc = t / RT, r = t % RT;
    sW[r * CsT + csrc] = Wdt[t];
  }
  for (int t = tid; t < CsT; t += 1024) sb2[t] = bdt[t];
  __syncthreads();
  // ---- stage 1: dt + u into LDS (float4 stores) ----
  {
    const int chunk_d = tid >> 4;
    const int sq4 = tid & 15;
    const int sq = sq4 * 4;
    const int lsrc = isU ? (c * 32 + (chunk_d >> 1)) : (c * 64 + chunk_d);
    const float* xrp = xdbl + (size_t)lsrc * ROW;
    float xr[8];
    for (int r = 0; r < RT; ++r) xr[r] = xrp[r];
    const float bcc = sb2[c];
    float dv[4], uv[4];
#pragma unroll
    for (int j = 0; j < 4; ++j) {
      int s = sq + j;
      int csrc = isU ? (((chunk_d & 1) << 6) + s) : s;
      float acc = sb2[csrc] + bcc;
      for (int r = 0; r < RT; ++r) acc += sW[r * CsT + csrc] * xr[r];
      int l = (chunk_d << 6) + s;
      dv[j] = softplusf(acc);
      uv[j] = Ub[isU ? l : (dir ? (L - 1 - l) : l)];
    }
    dtL4[chunk_d * 17 + sq4] = make_float4(dv[0], dv[1], dv[2], dv[3]);
    uL4[chunk_d * 17 + sq4]  = make_float4(uv[0], uv[1], uv[2], uv[3]);
  }
  __syncthreads();
  const int n = tid & 15;
  const int chunk = tid >> 4;
  const float a = -__expf(Alog[c * N + n]);
  const float* bp = xdbl + ((size_t)(chunk << 6)) * ROW + 16 + n;
  const float* cp = bp + 16;
  // phase A (float4 LDS reads)
  float ap = 1.f, h = 0.f;
#pragma unroll 4
  for (int m = 0; m < 16; ++m) {
    float4 d4 = dtL4[chunk * 17 + m];
    float4 u4 = uL4[chunk * 17 + m];
    float dv[4] = {d4.x, d4.y, d4.z, d4.w};
    float uv[4] = {u4.x, u4.y, u4.z, u4.w};
#pragma unroll
    for (int jj = 0; jj < 4; ++jj) {
      int s = (m << 2) + jj;
      float bn = bp[(size_t)s * ROW];
      float dA = __expf(dv[jj] * a);
      ap *= dA;
      h = h * dA + dv[jj] * uv[jj] * bn;
    }
  }
  sA[n][chunk] = ap; sH[n][chunk] = h;
  __syncthreads();
  // phase B: wave-parallel cross-chunk exclusive scan (wave w owns n=w)
  {
    const int w = tid >> 6;
    const int k = tid & 63;
    float A = sA[w][k];
    float Bv = sH[w][k];
#pragma unroll
    for (int j = 1; j < 64; j <<= 1) {
      float pa = __shfl_up(A, j);
      float pb = __shfl_up(Bv, j);
      if (k >= j) { Bv = pb * A + Bv; A = pa * A; }
    }
    float hprev = __shfl_up(Bv, 1);
    sH[w][k] = (k == 0) ? 0.f : hprev;
  }
  __syncthreads();
  h = sH[n][chunk];
  // phase C: 16-step batches + reduce-scatter (15 shfls per batch)
  const float Dc = Dv[c];
  const float* uLrow = (const float*)&uL4[chunk * 17];
  const bool h1 = (n & 1) != 0, h2 = (n & 2) != 0, h3 = (n & 4) != 0, h4 = (n & 8) != 0;
  float ybuf[4];
#pragma unroll
  for (int q = 0; q < 4; ++q) {
    float v[16];
#pragma unroll
    for (int m = 0; m < 4; ++m) {
      float4 d4 = dtL4[chunk * 17 + (q << 2) + m];
      float4 u4 = uL4[chunk * 17 + (q << 2) + m];
      float dv[4] = {d4.x, d4.y, d4.z, d4.w};
      float uv[4] = {u4.x, u4.y, u4.z, u4.w};
#pragma unroll
      for (int jj = 0; jj < 4; ++jj) {
        int s = (q << 4) + (m << 2) + jj;
        float bn = bp[(size_t)s * ROW];
        float cn = cp[(size_t)s * ROW];
        float dA = __expf(dv[jj] * a);
        h = h * dA + dv[jj] * uv[jj] * bn;
        v[(m << 2) + jj] = h * cn;
      }
    }
    float u8[8];
#pragma unroll
    for (int k2 = 0; k2 < 8; ++k2) {
      float snd = h1 ? v[2 * k2] : v[2 * k2 + 1];
      float t = __shfl_xor(snd, 1);
      u8[k2] = (h1 ? v[2 * k2 + 1] : v[2 * k2]) + t;
    }
    float u4a[4];
#pragma unroll
    for (int k2 = 0; k2 < 4; ++k2) {
      float snd = h2 ? u8[2 * k2] : u8[2 * k2 + 1];
      float t = __shfl_xor(snd, 2);
      u4a[k2] = (h2 ? u8[2 * k2 + 1] : u8[2 * k2]) + t;
    }
    float u2a[2];
#pragma unroll
    for (int k2 = 0; k2 < 2; ++k2) {
      float snd = h3 ? u4a[2 * k2] : u4a[2 * k2 + 1];
      float t = __shfl_xor(snd, 4);
      u2a[k2] = (h3 ? u4a[2 * k2 + 1] : u4a[2 * k2]) + t;
    }
    float snd = h4 ? u2a[0] : u2a[1];
    float t = __shfl_xor(snd, 8);
    float ysum = (h4 ? u2a[1] : u2a[0]) + t;
    float myu = uLrow[(q << 4) + n];
    ybuf[q] = ysum + myu * Dc;
  }
  if (!isU) {
    float* Yp = Y + (chunk << 6);
#pragma unroll
    for (int q = 0; q < 4; ++q) Yp[16 * q + n] = ybuf[q];
  } else {
    const int s0 = chunk << 6;
#pragma unroll
    for (int q = 0; q < 4; ++q) Y[idxb[s0 + 16 * q + n]] = ybuf[q];
  }
}

// ---------- gate1: PURE GEMM over [ycat | yu] + BN partial sums (scalar weights) ----------
template <int O_PB>
__global__ void k_gate1(const float* __restrict__ ycat, const float* __restrict__ yu,
                        const float* __restrict__ W, const float* __restrict__ bias,
                        float* __restrict__ g1, float* __restrict__ bnsum) {
  __shared__ float part[2][O_PB][4];
  const int o0 = blockIdx.y * O_PB;
  const int b  = blockIdx.z;
  const float* Wp = W + (size_t)o0 * 256;    // wave-uniform -> s_load
  const int l = blockIdx.x * TPB + threadIdx.x;
  const float* c0 = ycat + (size_t)b * C * L + l;
  const float* u0 = yu + (size_t)b * C * L + l;
  float acc[O_PB];
#pragma unroll
  for (int k = 0; k < O_PB; ++k) acc[k] = bias[o0 + k];
#pragma unroll 8
  for (int i = 0; i < 128; ++i) {
    float cv = c0[(size_t)i * L];
#pragma unroll
    for (int k = 0; k < O_PB; ++k) acc[k] += Wp[(size_t)k * 256 + i] * cv;
  }
#pragma unroll 8
  for (int i = 0; i < 128; ++i) {
    float xv = u0[(size_t)i * L];
#pragma unroll
    for (int k = 0; k < O_PB; ++k) acc[k] += Wp[(size_t)k * 256 + 128 + i] * xv;
  }
#pragma unroll
  for (int k = 0; k < O_PB; ++k)
    g1[((size_t)b * C + o0 + k) * L + l] = acc[k];
  const int wv = threadIdx.x >> 6, lnn = threadIdx.x & 63;
#pragma unroll
  for (int k = 0; k < O_PB; ++k) {
    float v = acc[k];
    v += __shfl_xor(v, 1);  v += __shfl_xor(v, 2);  v += __shfl_xor(v, 4);
    v += __shfl_xor(v, 8);  v += __shfl_xor(v, 16); v += __shfl_xor(v, 32);
    if (lnn == 0) part[0][k][wv] = v;
    float q = acc[k] * acc[k];
    q += __shfl_xor(q, 1);  q += __shfl_xor(q, 2);  q += __shfl_xor(q, 4);
    q += __shfl_xor(q, 8);  q += __shfl_xor(q, 16); q += __shfl_xor(q, 32);
    if (lnn == 0) part[1][k][wv] = q;
  }
  __syncthreads();
  if (threadIdx.x < 2 * O_PB) {
    int which = threadIdx.x >= O_PB, k = threadIdx.x % O_PB;
    float v = part[which][k][0] + part[which][k][1] + part[which][k][2] + part[which][k][3];
    atomicAdd(&bnsum[which * 128 + o0 + k], v);
  }
}

// ---------- gate2: BN(from sums)+relu on loads; epilogue sigmoid + fuse (scalar weights) ----------
template <int O_PB>
__global__ void k_gate2_fuse(const float* __restrict__ g1,
                             const float* __restrict__ bnsum,
                             const float* __restrict__ bn_g, const float* __restrict__ bn_b,
                             const float* __restrict__ W, const float* __restrict__ bias,
                             const float* __restrict__ yu, const float* __restrict__ ycat,
                             float* __restrict__ fused) {
  __shared__ float sc[128], sh[128];
  const int o0 = blockIdx.y * O_PB;
  const int b  = blockIdx.z;
  for (int t = threadIdx.x; t < 128; t += TPB) {
    float sv = bnsum[t], qv = bnsum[128 + t];
    float mean = sv / (B_SZ * L);
    float var  = qv / (B_SZ * L) - mean * mean;
    float scv = bn_g[t] * rsqrtf(var + 1e-5f);
    sc[t] = scv;
    sh[t] = bn_b[t] - mean * scv;
  }
  __syncthreads();
  const float* Wp = W + (size_t)o0 * 128;    // wave-uniform -> s_load
  const int l = blockIdx.x * TPB + threadIdx.x;
  const float* Xb = g1 + (size_t)b * C * L + l;
  float acc[O_PB];
#pragma unroll
  for (int k = 0; k < O_PB; ++k) acc[k] = bias[o0 + k];
#pragma unroll 8
  for (int i = 0; i < 128; ++i) {
    float v = fmaxf(Xb[(size_t)i * L] * sc[i] + sh[i], 0.f);
#pragma unroll
    for (int k = 0; k < O_PB; ++k) acc[k] += Wp[(size_t)k * 128 + i] * v;
  }
#pragma unroll
  for (int k = 0; k < O_PB; ++k) {
    int o = o0 + k;
    float g = sigm(acc[k]);
    float yuv = yu[((size_t)b * C + o) * L + l];
    float cv = ycat[((size_t)b * C + o) * L + l];
    fused[((size_t)b * C + o) * L + l] = g * yuv + (1.f - g) * cv;
  }
}

// ---------- outproj: 1x1 conv over concat([fused, xr]) + atomic LN stats (scalar weights) ----------
template <int O_PB>
__global__ void k_outproj(const float* __restrict__ X1, const float* __restrict__ X2,
                          const float* __restrict__ W, const float* __restrict__ bias,
                          float* __restrict__ Y,
                          float* __restrict__ st3s, float* __restrict__ st3q) {
  const int o0 = blockIdx.y * O_PB;
  const int b  = blockIdx.z;
  const float* Wp = W + (size_t)o0 * 256;    // wave-uniform -> s_load
  const int l = blockIdx.x * TPB + threadIdx.x;
  const float* Xb1 = X1 + (size_t)b * C * L + l;
  const float* Xb2 = X2 + (size_t)b * C * L + l;
  float acc[O_PB];
#pragma unroll
  for (int k = 0; k < O_PB; ++k) acc[k] = bias[o0 + k];
#pragma unroll 8
  for (int i = 0; i < 128; ++i) {
    float xv = Xb1[(size_t)i * L];
#pragma unroll
    for (int k = 0; k < O_PB; ++k) acc[k] += Wp[(size_t)k * 256 + i] * xv;
  }
#pragma unroll 8
  for (int i = 0; i < 128; ++i) {
    float xv = Xb2[(size_t)i * L];
#pragma unroll
    for (int k = 0; k < O_PB; ++k) acc[k] += Wp[(size_t)k * 256 + 128 + i] * xv;
  }
  float ss = 0.f, qq = 0.f;
#pragma unroll
  for (int k = 0; k < O_PB; ++k) {
    Y[((size_t)b * C + o0 + k) * L + l] = acc[k];
    ss += acc[k]; qq += acc[k] * acc[k];
  }
  atomicAdd(&st3s[b * L + l], ss);
  atomicAdd(&st3q[b * L + l], qq);
}

// ---------- final channel LN from precomputed stats: fully-parallel float4 ----------
__global__ void k_ln_out(const float* __restrict__ X,
                         const float* __restrict__ st3s, const float* __restrict__ st3q,
                         const float* __restrict__ w, const float* __restrict__ bchan,
                         float* __restrict__ Y) {
  const int t  = blockIdx.x * TPB + threadIdx.x;   // float4 index
  const int gi = t * 4;
  const int l  = gi % L;
  const int c  = (gi / L) % C;
  const int b  = gi / (C * L);
  const float4 v  = ((const float4*)X)[t];
  const float4 s4 = *(const float4*)(st3s + b * L + l);
  const float4 q4 = *(const float4*)(st3q + b * L + l);
  const float wc = w[c], bc = bchan[c];
  float4 o;
  {
    float m = s4.x * (1.f / C);
    float r = rsqrtf(q4.x * (1.f / C) - m * m + 1e-6f);
    o.x = wc * (v.x - m) * r + bc;
  }
  {
    float m = s4.y * (1.f / C);
    float r = rsqrtf(q4.y * (1.f / C) - m * m + 1e-6f);
    o.y = wc * (v.y - m) * r + bc;
  }
  {
    float m = s4.z * (1.f / C);
    float r = rsqrtf(q4.z * (1.f / C) - m * m + 1e-6f);
    o.z = wc * (v.z - m) * r + bc;
  }
  {
    float m = s4.w * (1.f / C);
    float r = rsqrtf(q4.w * (1.f / C) - m * m + 1e-6f);
    o.w = wc * (v.w - m) * r + bc;
  }
  ((float4*)Y)[t] = o;
}

} // namespace

extern "C" void kernel_launch(void* const* d_in, const int* in_sizes, int n_in,
                              void* d_out, int out_size, void* d_ws, size_t ws_size,
                              hipStream_t stream) {
  const float* x         = (const float*)d_in[0];
  const float* ln_in_w   = (const float*)d_in[1];
  const float* ln_in_b   = (const float*)d_in[2];
  const float* inproj_w  = (const float*)d_in[3];
  const float* inproj_b  = (const float*)d_in[4];
  const float* ln_m_w    = (const float*)d_in[5];
  const float* ln_m_b    = (const float*)d_in[6];
  const float* convm_w   = (const float*)d_in[7];
  const float* convm_b   = (const float*)d_in[8];
  const float* convr_w   = (const float*)d_in[9];
  const float* convr_b   = (const float*)d_in[10];
  const float* ln_cat_w  = (const float*)d_in[11];
  const float* ln_cat_b  = (const float*)d_in[12];
  const float* xpf_w     = (const float*)d_in[13];
  const float* xpf_b     = (const float*)d_in[14];
  const float* dtf_w     = (const float*)d_in[15];
  const float* dtf_b     = (const float*)d_in[16];
  const float* Alog_f    = (const float*)d_in[17];
  const float* D_f       = (const float*)d_in[18];
  const float* xpb_w     = (const float*)d_in[19];
  const float* xpb_b     = (const float*)d_in[20];
  const float* dtb_w     = (const float*)d_in[21];
  const float* dtb_b     = (const float*)d_in[22];
  const float* Alog_b    = (const float*)d_in[23];
  const float* D_b       = (const float*)d_in[24];
  const float* xpu_w     = (const float*)d_in[25];
  const float* xpu_b     = (const float*)d_in[26];
  const float* dtu_w     = (const float*)d_in[27];
  const float* dtu_b     = (const float*)d_in[28];
  const float* Alog_u    = (const float*)d_in[29];
  const float* D_u       = (const float*)d_in[30];
  const float* gate1_w   = (const float*)d_in[31];
  const float* gate1_b   = (const float*)d_in[32];
  const float* bn_g      = (const float*)d_in[33];
  const float* bn_b      = (const float*)d_in[34];
  const float* gate2_w   = (const float*)d_in[35];
  const float* gate2_b   = (const float*)d_in[36];
  const float* outproj_w = (const float*)d_in[37];
  const float* outproj_b = (const float*)d_in[38];
  const float* outln_w   = (const float*)d_in[39];
  const float* outln_b   = (const float*)d_in[40];

  float* ws = (float*)d_ws;
  size_t off = 0;
  auto alloc = [&](size_t n) { float* p = ws + off; off += n; return p; };

  const size_t BL = (size_t)B_SZ * L;
  // zero-initialized region (one memset): st1s, st1q, st3s, st3q, rank, bnsum — contiguous
  float* st1s  = alloc(BL);
  float* st1q  = alloc(BL);
  float* st3s  = alloc(BL);
  float* st3q  = alloc(BL);
  int*   rank  = (int*)alloc(BL);
  float* bnsum = alloc(256);
  const size_t zeroBytes = (5 * BL + 256) * sizeof(float);

  float* xln   = alloc((size_t)B_SZ * C * L);
  float* xp    = alloc((size_t)B_SZ * 2 * C * L);
  float* xm    = alloc((size_t)B_SZ * C * L);
  float* xr    = alloc((size_t)B_SZ * C * L);
  float* unc   = alloc(BL);
  int*   idx   = (int*)alloc(BL);
  float* xs    = alloc((size_t)B_SZ * C * L);
  float* xdblF = alloc((size_t)4 * L * ROW);
  float* xdblU = alloc((size_t)2 * L * ROW);
  float* yf    = alloc((size_t)B_SZ * HALF * L);
  float* yb    = alloc((size_t)B_SZ * HALF * L);
  float* yu    = alloc((size_t)B_SZ * C * L);
  float* ycat  = alloc((size_t)B_SZ * C * L);
  float* g1    = alloc((size_t)B_SZ * C * L);
  float* fused = alloc((size_t)B_SZ * C * L);
  float* outp  = alloc((size_t)B_SZ * C * L);
  (void)ws_size; (void)in_sizes; (void)n_in; (void)out_size;

  const int pixB   = B_SZ * L / 64;        // 128 blocks (256 thr)
  const int pixB32 = B_SZ * L / 32;        // 256 blocks (256 thr, 32 px each)

  // 0) zero the accumulators — one small async fill
  hipMemsetAsync(st1s, 0, zeroBytes, stream);
  // 1) input pixel-LN, then pure inproj GEMM (scalar weights) + st1 stats
  k_pixln<<<pixB32, TPB, 0, stream>>>(x, ln_in_w, ln_in_b, xln);
  k_conv_in<<<dim3(L / TPB, 32, B_SZ), TPB, 0, stream>>>(
      xln, inproj_w, inproj_b, xp, st1s, st1q);
  // 2) tiled dwconv (mamba LN from sums, res plain)
  k_dwconv_t<<<dim3(HH / 4, C, 2 * B_SZ), TPB, 0, stream>>>(
      xp, st1s, st1q, ln_m_w, ln_m_b, convm_w, convm_b, convr_w, convr_b, xm, xr);
  // 3) unc, rank-count (byte-identical), invert idx, gather xs
  k_unc<<<pixB, TPB, 0, stream>>>(xm, unc);
  k_rank<<<dim3(L / TPB, 8, B_SZ), TPB, 0, stream>>>(unc, rank);
  k_invidx<<<B_SZ * L / TPB, TPB, 0, stream>>>(rank, idx);
  k_gather<<<dim3(L / TPB, 16, B_SZ), TPB, 0, stream>>>(xm, idx, xs);
  // 4) x-projections into padded ROW=48 layout; merged scan
  k_convx_all<<<dim3(L / TPB, 10, 6), TPB, 0, stream>>>(
      xm, xs, xpf_w, xpf_b, xpb_w, xpb_b, xpu_w, xpu_b, xdblF, xdblU);
  k_scan_all<<<512, 1024, 0, stream>>>(
      xdblF, xdblU, dtf_w, dtf_b, dtb_w, dtb_b, dtu_w, dtu_b,
      xm, xs, idx, Alog_f, Alog_b, Alog_u, D_f, D_b, D_u, yf, yb, yu);
  // 5) epilogue: cat-LN once, then three pure GEMMs (scalar weights), stats via atomics
  k_lncat<<<pixB32, TPB, 0, stream>>>(yf, yb, ln_cat_w, ln_cat_b, ycat);
  k_gate1<8><<<dim3(L / TPB, 16, B_SZ), TPB, 0, stream>>>(
      ycat, yu, gate1_w, gate1_b, g1, bnsum);
  k_gate2_fuse<8><<<dim3(L / TPB, 16, B_SZ), TPB, 0, stream>>>(
      g1, bnsum, bn_g, bn_b, gate2_w, gate2_b, yu, ycat, fused);
  k_outproj<8><<<dim3(L / TPB, 16, B_SZ), TPB, 0, stream>>>(
      fused, xr, outproj_w, outproj_b, outp, st3s, st3q);
  k_ln_out<<<(B_SZ * C * L / 4) / TPB, TPB, 0, stream>>>(
      outp, st3s, st3q, outln_w, outln_b, (float*)d_out);
}

// Round 4
// 290.399 us; speedup vs baseline: 1.0530x; 1.0530x over previous
//
#include <hip/hip_runtime.h>
#include <cstdint>
#include <cstddef>

#define TPB 256

namespace {

constexpr int B_SZ = 2;
constexpr int C    = 128;
constexpr int HALF = 64;
constexpr int L    = 4096;   // 64*64
constexpr int N    = 16;
constexpr int HH   = 64;
constexpr int WW   = 64;
// padded x_dbl row: [dt 0..RT) | pad | B 16..32 | C 32..48  (192B = 64B-aligned B/C)
constexpr int ROW  = 48;

// fast-math (hardware v_exp_f32/v_log_f32); ~1e-7 rel err, fine at 9.7e-2 threshold
__device__ __forceinline__ float softplusf(float x) {
  return fmaxf(x, 0.f) + __logf(1.f + __expf(-fabsf(x)));
}
__device__ __forceinline__ float sigm(float x) { return 1.f / (1.f + __expf(-x)); }

__device__ __forceinline__ unsigned long long unc_key(float u, int i) {
  unsigned m = __float_as_uint(u);
  m = (m & 0x80000000u) ? ~m : (m | 0x80000000u);   // monotone ascending map
  return ((unsigned long long)(~m) << 32) | (unsigned)i;  // ascending = descending unc, stable
}

// ---------- per-pixel channel LN over 128 channels (CHW): Y = w*(x-m)*r + b ----------
__global__ void k_pixln(const float* __restrict__ X, const float* __restrict__ w,
                        const float* __restrict__ bchan, float* __restrict__ Y) {
  const int px = threadIdx.x & 31;
  const int g  = threadIdx.x >> 5;
  const int p  = blockIdx.x * 32 + px;
  const int b  = p / L, l = p % L;
  const float* Xp = X + (size_t)b * C * L + l;
  float v[16];
  float s = 0.f, s2 = 0.f;
#pragma unroll
  for (int j = 0; j < 16; ++j) {
    float t = Xp[(size_t)(g * 16 + j) * L];
    v[j] = t; s += t; s2 += t * t;
  }
  __shared__ float red[2][8][32];
  red[0][g][px] = s; red[1][g][px] = s2;
  __syncthreads();
  float st = 0.f, qt = 0.f;
#pragma unroll
  for (int k = 0; k < 8; ++k) { st += red[0][k][px]; qt += red[1][k][px]; }
  const float m = st * (1.f / C);
  const float r = rsqrtf(qt * (1.f / C) - m * m + 1e-6f);
  float* Yp = Y + (size_t)b * C * L + l;
#pragma unroll
  for (int j = 0; j < 16; ++j) {
    int c = g * 16 + j;
    Yp[(size_t)c * L] = w[c] * (v[j] - m) * r + bchan[c];
  }
}

// ---------- cat-LN: ycat = LN(concat(yf, rev(yb))) ----------
__global__ void k_lncat(const float* __restrict__ yf, const float* __restrict__ yb,
                        const float* __restrict__ w, const float* __restrict__ bchan,
                        float* __restrict__ Y) {
  const int px = threadIdx.x & 31;
  const int g  = threadIdx.x >> 5;
  const int p  = blockIdx.x * 32 + px;
  const int b  = p / L, l = p % L;
  float v[16];
  float s = 0.f, s2 = 0.f;
#pragma unroll
  for (int j = 0; j < 16; ++j) {
    int c = g * 16 + j;
    float t = (c < 64) ? yf[((size_t)b * HALF + c) * L + l]
                       : yb[((size_t)b * HALF + (c - 64)) * L + (L - 1 - l)];
    v[j] = t; s += t; s2 += t * t;
  }
  __shared__ float red[2][8][32];
  red[0][g][px] = s; red[1][g][px] = s2;
  __syncthreads();
  float st = 0.f, qt = 0.f;
#pragma unroll
  for (int k = 0; k < 8; ++k) { st += red[0][k][px]; qt += red[1][k][px]; }
  const float m = st * (1.f / C);
  const float r = rsqrtf(qt * (1.f / C) - m * m + 1e-6f);
  float* Yp = Y + (size_t)b * C * L + l;
#pragma unroll
  for (int j = 0; j < 16; ++j) {
    int c = g * 16 + j;
    Yp[(size_t)c * L] = w[c] * (v[j] - m) * r + bchan[c];
  }
}

// ---------- inproj: pure 1x1 conv on pre-normalized xln + atomic stats of xp[:,:128] ----------
__global__ void k_conv_in(const float* __restrict__ X,
                          const float* __restrict__ W, const float* __restrict__ bias,
                          float* __restrict__ Y,
                          float* __restrict__ st1s, float* __restrict__ st1q) {
  constexpr int O_PB = 8;
  __shared__ float Wl[O_PB * 128];
  const int o0 = blockIdx.y * O_PB;
  const int b  = blockIdx.z;
  for (int t = threadIdx.x; t < O_PB * 128; t += TPB) {
    int i = t / O_PB, k = t % O_PB;
    Wl[t] = W[(size_t)(o0 + k) * 128 + i];
  }
  __syncthreads();
  const int l = blockIdx.x * TPB + threadIdx.x;
  const float* X0 = X + (size_t)b * C * L + l;
  float acc[O_PB];
#pragma unroll
  for (int k = 0; k < O_PB; ++k) acc[k] = bias[o0 + k];
#pragma unroll 8
  for (int i = 0; i < 128; ++i) {
    float xv = X0[(size_t)i * L];
#pragma unroll
    for (int k = 0; k < O_PB; ++k) acc[k] += Wl[i * O_PB + k] * xv;
  }
#pragma unroll
  for (int k = 0; k < O_PB; ++k)
    Y[((size_t)b * 256 + o0 + k) * L + l] = acc[k];
  if (o0 < 128) {
    float ss = 0.f, qq = 0.f;
#pragma unroll
    for (int k = 0; k < O_PB; ++k) { ss += acc[k]; qq += acc[k] * acc[k]; }
    atomicAdd(&st1s[b * L + l], ss);
    atomicAdd(&st1q[b * L + l], qq);
  }
}

// ---------- depthwise 3x3 + SiLU via LDS halo tile; mode0 LN (from sum/sumsq) ----------
__global__ void k_dwconv_t(const float* __restrict__ xp,
                           const float* __restrict__ st1s, const float* __restrict__ st1q,
                           const float* __restrict__ lnw, const float* __restrict__ lnb,
                           const float* __restrict__ Wm, const float* __restrict__ bm,
                           const float* __restrict__ Wr, const float* __restrict__ br,
                           float* __restrict__ xm, float* __restrict__ xr) {
  const int c = blockIdx.y;
  const int z = blockIdx.z;
  const int b = z & 1, mode = z >> 1;     // 0: mamba (LN), 1: res
  const int h0 = blockIdx.x * 4;
  __shared__ float T[6][66];
  const float* Xc = xp + ((size_t)b * 2 * C + (mode ? C + c : c)) * L;
  const float lw = mode ? 0.f : lnw[c];
  const float lb2 = mode ? 0.f : lnb[c];
  for (int t = threadIdx.x; t < 6 * 66; t += TPB) {
    int r = t / 66, cc = t % 66 - 1;
    int hh = h0 - 1 + r;
    float v = 0.f;
    if (hh >= 0 && hh < HH && cc >= 0 && cc < WW) {
      int li = hh * WW + cc;
      v = Xc[li];
      if (mode == 0) {
        float sv = st1s[b * L + li], qv = st1q[b * L + li];
        float m = sv * (1.f / 128.f);
        float rr = rsqrtf(qv * (1.f / 128.f) - m * m + 1e-6f);
        v = (v - m) * rr * lw + lb2;
      }
    }
    T[r][t % 66] = v;
  }
  __syncthreads();
  const int hl = threadIdx.x >> 6, w = threadIdx.x & 63;
  const float* W9 = (mode ? Wr : Wm) + c * 9;
  float acc = mode ? br[c] : bm[c];
#pragma unroll
  for (int kh = 0; kh < 3; ++kh)
#pragma unroll
    for (int kw = 0; kw < 3; ++kw)
      acc += T[hl + kh][w + kw] * W9[kh * 3 + kw];
  const int l = (h0 + hl) * WW + w;
  float* Yp = mode ? xr : xm;
  Yp[((size_t)b * C + c) * L + l] = acc * sigm(acc);
}

// ---------- uncertainty per pixel (kept byte-identical: preserves sort dice) ----------
__global__ void k_unc(const float* __restrict__ xm, float* __restrict__ unc) {
  const int lp = threadIdx.x & 63;
  const int wv = threadIdx.x >> 6;
  const int p  = blockIdx.x * 64 + lp;
  const int b = p / L, l = p % L;
  const float* Xp = xm + (size_t)b * C * L + l;
  float s = 0.f;
#pragma unroll 8
  for (int i = 0; i < 32; ++i) s += Xp[(size_t)(wv * 32 + i) * L];
  __shared__ float r1[4][64];
  r1[wv][lp] = s;
  __syncthreads();
  if (wv == 0) {
    float st = r1[0][lp] + r1[1][lp] + r1[2][lp] + r1[3][lp];
    float sg = sigm(st / C);
    unc[p] = -(sg * __logf(sg + 1e-6f));
  }
}

// ---------- stable rank of descending unc: rank_i = #{j: ckey_j < ckey_i} ----------
__global__ void k_rank(const float* __restrict__ unc, int* __restrict__ rankbuf) {
  constexpr int JC = 512;
  __shared__ unsigned long long K[JC];
  const int b  = blockIdx.z;
  const int j0 = blockIdx.y * JC;
  const int i  = blockIdx.x * TPB + threadIdx.x;
  for (int t = threadIdx.x; t < JC; t += TPB)
    K[t] = unc_key(unc[b * L + j0 + t], j0 + t);
  __syncthreads();
  const unsigned long long my = unc_key(unc[b * L + i], i);
  int cnt = 0;
#pragma unroll 8
  for (int j = 0; j < JC; ++j) cnt += (K[j] < my) ? 1 : 0;
  atomicAdd(&rankbuf[b * L + i], cnt);
}

// ---------- scatter-gather: xs[b,c,rank_l] = xm[b,c,l]; idx[r]=l ----------
__global__ void k_scatgath(const float* __restrict__ xm, const int* __restrict__ rankbuf,
                           float* __restrict__ xs, int* __restrict__ idx) {
  int t = blockIdx.x * TPB + threadIdx.x;
  int l = t % L, c = (t / L) % C, b = t / (C * L);
  int r = rankbuf[b * L + l];
  xs[((size_t)b * C + c) * L + r] = xm[t];
  if (c == 0) idx[b * L + r] = l;
}

// ---------- merged x-projection conv: z 0..3 = f/b dirs, z 4..5 = u (reads xs) ----------
// writes into padded ROW=48 layout (dt at 0..RT, B at 16..32, C at 32..48)
__global__ void k_convx_all(const float* __restrict__ xm, const float* __restrict__ xs,
                            const float* __restrict__ Wf, const float* __restrict__ bf,
                            const float* __restrict__ Wb, const float* __restrict__ bb,
                            const float* __restrict__ Wu, const float* __restrict__ bu,
                            float* __restrict__ XDF, float* __restrict__ XDU) {
  const int z = blockIdx.z;
  const bool isU = z >= 4;
  const int I = isU ? 128 : 64;
  const int O = isU ? 40 : 36;
  const int RT = isU ? 8 : 4;
  const int o0 = blockIdx.y * 4;
  if (o0 >= O) return;                 // block-uniform
  int b, dir;
  const float *W, *bi;
  if (!isU) { dir = z >> 1; b = z & 1; W = dir ? Wb : Wf; bi = dir ? bb : bf; }
  else      { dir = 0; b = z - 4; W = Wu; bi = bu; }
  __shared__ float Wl[4 * 128];
  for (int t = threadIdx.x; t < 4 * I; t += TPB) {
    int i = t / 4, k = t % 4;
    Wl[t] = W[(size_t)(o0 + k) * I + i];
  }
  __syncthreads();
  const int l = blockIdx.x * TPB + threadIdx.x;
  const int ls = isU ? l : (dir ? (L - 1 - l) : l);
  const float* Xb = isU ? (xs + (size_t)b * C * L)
                        : (xm + ((size_t)b * C + dir * HALF) * L);
  float acc[4];
#pragma unroll
  for (int k = 0; k < 4; ++k) acc[k] = bi[o0 + k];
#pragma unroll 8
  for (int i = 0; i < I; ++i) {
    float xv = Xb[(size_t)i * L + ls];
#pragma unroll
    for (int k = 0; k < 4; ++k) acc[k] += Wl[i * 4 + k] * xv;
  }
  const int slot0 = (o0 < RT) ? o0 : o0 + (16 - RT);
  float* yp = isU ? (XDU + ((size_t)b * L + l) * ROW + slot0)
                  : (XDF + ((size_t)z * L + l) * ROW + slot0);
#pragma unroll
  for (int k = 0; k < 4; ++k) yp[k] = acc[k];
}

// ---------- merged fused selective scan (512 blocks); U writes UNSORTED via idx ----------
// B/C prefetched into registers in 16-step groups (double-buffered) to hide L2 latency.
__global__ __launch_bounds__(1024) void
k_scan_all(const float* __restrict__ xdblF, const float* __restrict__ xdblU,
           const float* __restrict__ dtf_w, const float* __restrict__ dtf_b,
           const float* __restrict__ dtb_w, const float* __restrict__ dtb_b,
           const float* __restrict__ dtu_w, const float* __restrict__ dtu_b,
           const float* __restrict__ xm, const float* __restrict__ xs,
           const int* __restrict__ idx,
           const float* __restrict__ Alog_f, const float* __restrict__ Alog_b,
           const float* __restrict__ Alog_u,
           const float* __restrict__ D_f, const float* __restrict__ D_b,
           const float* __restrict__ D_u,
           float* __restrict__ yf, float* __restrict__ yb, float* __restrict__ yu) {
  const int blk = blockIdx.x;
  const int tid = threadIdx.x;
  const bool isU = blk >= 256;
  int CsT, RT, c, b, dir;
  const float *Wdt, *bdt, *Alog, *Dv, *xdbl, *Ub;
  const int* idxb = nullptr;
  float* Y;
  if (!isU) {
    CsT = 64; RT = 4;
    int zb = blk >> 6; c = blk & 63; dir = zb >> 1; b = zb & 1;
    Wdt = dir ? dtb_w : dtf_w; bdt = dir ? dtb_b : dtf_b;
    Alog = dir ? Alog_b : Alog_f; Dv = dir ? D_b : D_f;
    xdbl = xdblF + (size_t)zb * L * ROW;
    Ub = xm + ((size_t)b * C + dir * HALF + c) * L;
    Y = (dir ? yb : yf) + ((size_t)b * HALF + c) * L;
  } else {
    CsT = 128; RT = 8;
    int blk2 = blk - 256; b = blk2 >> 7; c = blk2 & 127; dir = 0;
    Wdt = dtu_w; bdt = dtu_b; Alog = Alog_u; Dv = D_u;
    xdbl = xdblU + (size_t)b * L * ROW;
    Ub = xs + ((size_t)b * C + c) * L;
    idxb = idx + b * L;
    Y = yu + ((size_t)b * C + c) * L;
  }
  __shared__ float sW[1024];            // transposed: sW[r*CsT + csrc]
  __shared__ float sb2[128];
  __shared__ float4 dtL4[64 * 17];      // d  (row = 17 float4 = 68 floats, 16B-aligned)
  __shared__ float4 uL4[64 * 17];       // u
  __shared__ float sA[N][65], sH[N][65];
  for (int t = tid; t < CsT * RT; t += 1024) {
    int csrc = t / RT, r = t % RT;
    sW[r * CsT + csrc] = Wdt[t];
  }
  for (int t = tid; t < CsT; t += 1024) sb2[t] = bdt[t];
  __syncthreads();
  // ---- stage 1: dt + u into LDS (float4 stores) ----
  {
    const int chunk_d = tid >> 4;
    const int sq4 = tid & 15;
    const int sq = sq4 * 4;
    const int lsrc = isU ? (c * 32 + (chunk_d >> 1)) : (c * 64 + chunk_d);
    const float* xrp = xdbl + (size_t)lsrc * ROW;
    float xr[8];
    for (int r = 0; r < RT; ++r) xr[r] = xrp[r];
    const float bcc = sb2[c];
    float dv[4], uv[4];
#pragma unroll
    for (int j = 0; j < 4; ++j) {
      int s = sq + j;
      int csrc = isU ? (((chunk_d & 1) << 6) + s) : s;
      float acc = sb2[csrc] + bcc;
      for (int r = 0; r < RT; ++r) acc += sW[r * CsT + csrc] * xr[r];
      int l = (chunk_d << 6) + s;
      dv[j] = softplusf(acc);
      uv[j] = Ub[isU ? l : (dir ? (L - 1 - l) : l)];
    }
    dtL4[chunk_d * 17 + sq4] = make_float4(dv[0], dv[1], dv[2], dv[3]);
    uL4[chunk_d * 17 + sq4]  = make_float4(uv[0], uv[1], uv[2], uv[3]);
  }
  __syncthreads();
  const int n = tid & 15;
  const int chunk = tid >> 4;
  const float a = -__expf(Alog[c * N + n]);
  const float* bp = xdbl + ((size_t)(chunk << 6)) * ROW + 16 + n;
  const float* cp = bp + 16;
  // phase A: B prefetched in 16-step register groups (double-buffered)
  float ap = 1.f, h = 0.f;
  {
    float bcur[16], bnxt[16];
#pragma unroll
    for (int j = 0; j < 16; ++j) bcur[j] = bp[(size_t)j * ROW];
#pragma unroll
    for (int g = 0; g < 4; ++g) {
      if (g < 3) {
#pragma unroll
        for (int j = 0; j < 16; ++j) bnxt[j] = bp[(size_t)((g + 1) * 16 + j) * ROW];
      }
#pragma unroll
      for (int m = 0; m < 4; ++m) {
        float4 d4 = dtL4[chunk * 17 + (g << 2) + m];
        float4 u4 = uL4[chunk * 17 + (g << 2) + m];
        float dv[4] = {d4.x, d4.y, d4.z, d4.w};
        float uv[4] = {u4.x, u4.y, u4.z, u4.w};
#pragma unroll
        for (int jj = 0; jj < 4; ++jj) {
          float bn = bcur[(m << 2) + jj];
          float dA = __expf(dv[jj] * a);
          ap *= dA;
          h = h * dA + dv[jj] * uv[jj] * bn;
        }
      }
#pragma unroll
      for (int j = 0; j < 16; ++j) bcur[j] = bnxt[j];
    }
  }
  sA[n][chunk] = ap; sH[n][chunk] = h;
  __syncthreads();
  // phase B: wave-parallel cross-chunk exclusive scan (wave w owns n=w)
  {
    const int w = tid >> 6;
    const int k = tid & 63;
    float A = sA[w][k];
    float Bv = sH[w][k];
#pragma unroll
    for (int j = 1; j < 64; j <<= 1) {
      float pa = __shfl_up(A, j);
      float pb = __shfl_up(Bv, j);
      if (k >= j) { Bv = pb * A + Bv; A = pa * A; }
    }
    float hprev = __shfl_up(Bv, 1);
    sH[w][k] = (k == 0) ? 0.f : hprev;
  }
  __syncthreads();
  h = sH[n][chunk];
  // phase C: 16-step batches, B/C double-buffered in registers + reduce-scatter
  const float Dc = Dv[c];
  const float* uLrow = (const float*)&uL4[chunk * 17];
  const bool h1 = (n & 1) != 0, h2 = (n & 2) != 0, h3 = (n & 4) != 0, h4 = (n & 8) != 0;
  float ybuf[4];
  float bq[16], cq[16], bq2[16], cq2[16];
#pragma unroll
  for (int j = 0; j < 16; ++j) {
    bq[j] = bp[(size_t)j * ROW];
    cq[j] = cp[(size_t)j * ROW];
  }
#pragma unroll
  for (int q = 0; q < 4; ++q) {
    if (q < 3) {
#pragma unroll
      for (int j = 0; j < 16; ++j) {
        bq2[j] = bp[(size_t)((q + 1) * 16 + j) * ROW];
        cq2[j] = cp[(size_t)((q + 1) * 16 + j) * ROW];
      }
    }
    float v[16];
#pragma unroll
    for (int m = 0; m < 4; ++m) {
      float4 d4 = dtL4[chunk * 17 + (q << 2) + m];
      float4 u4 = uL4[chunk * 17 + (q << 2) + m];
      float dv[4] = {d4.x, d4.y, d4.z, d4.w};
      float uv[4] = {u4.x, u4.y, u4.z, u4.w};
#pragma unroll
      for (int jj = 0; jj < 4; ++jj) {
        int sl = (m << 2) + jj;
        float bn = bq[sl];
        float cn = cq[sl];
        float dA = __expf(dv[jj] * a);
        h = h * dA + dv[jj] * uv[jj] * bn;
        v[sl] = h * cn;
      }
    }
    float u8[8];
#pragma unroll
    for (int k2 = 0; k2 < 8; ++k2) {
      float snd = h1 ? v[2 * k2] : v[2 * k2 + 1];
      float t = __shfl_xor(snd, 1);
      u8[k2] = (h1 ? v[2 * k2 + 1] : v[2 * k2]) + t;
    }
    float u4a[4];
#pragma unroll
    for (int k2 = 0; k2 < 4; ++k2) {
      float snd = h2 ? u8[2 * k2] : u8[2 * k2 + 1];
      float t = __shfl_xor(snd, 2);
      u4a[k2] = (h2 ? u8[2 * k2 + 1] : u8[2 * k2]) + t;
    }
    float u2a[2];
#pragma unroll
    for (int k2 = 0; k2 < 2; ++k2) {
      float snd = h3 ? u4a[2 * k2] : u4a[2 * k2 + 1];
      float t = __shfl_xor(snd, 4);
      u2a[k2] = (h3 ? u4a[2 * k2 + 1] : u4a[2 * k2]) + t;
    }
    float snd = h4 ? u2a[0] : u2a[1];
    float t = __shfl_xor(snd, 8);
    float ysum = (h4 ? u2a[1] : u2a[0]) + t;
    float myu = uLrow[(q << 4) + n];
    ybuf[q] = ysum + myu * Dc;
#pragma unroll
    for (int j = 0; j < 16; ++j) { bq[j] = bq2[j]; cq[j] = cq2[j]; }
  }
  if (!isU) {
    float* Yp = Y + (chunk << 6);
#pragma unroll
    for (int q = 0; q < 4; ++q) Yp[16 * q + n] = ybuf[q];
  } else {
    const int s0 = chunk << 6;
#pragma unroll
    for (int q = 0; q < 4; ++q) Y[idxb[s0 + 16 * q + n]] = ybuf[q];
  }
}

// ---------- gate1: PURE GEMM over [ycat | yu] + BN partial sums ----------
template <int O_PB>
__global__ void k_gate1(const float* __restrict__ ycat, const float* __restrict__ yu,
                        const float* __restrict__ W, const float* __restrict__ bias,
                        float* __restrict__ g1, float* __restrict__ bnsum) {
  __shared__ float Wl[O_PB * 256];
  __shared__ float part[2][O_PB][4];
  const int o0 = blockIdx.y * O_PB;
  const int b  = blockIdx.z;
  for (int t = threadIdx.x; t < O_PB * 256; t += TPB) {
    int i = t / O_PB, k = t % O_PB;
    Wl[t] = W[(size_t)(o0 + k) * 256 + i];
  }
  __syncthreads();
  const int l = blockIdx.x * TPB + threadIdx.x;
  const float* c0 = ycat + (size_t)b * C * L + l;
  const float* u0 = yu + (size_t)b * C * L + l;
  float acc[O_PB];
#pragma unroll
  for (int k = 0; k < O_PB; ++k) acc[k] = bias[o0 + k];
#pragma unroll 8
  for (int i = 0; i < 128; ++i) {
    float cv = c0[(size_t)i * L];
#pragma unroll
    for (int k = 0; k < O_PB; ++k) acc[k] += Wl[i * O_PB + k] * cv;
  }
#pragma unroll 8
  for (int i = 0; i < 128; ++i) {
    float xv = u0[(size_t)i * L];
#pragma unroll
    for (int k = 0; k < O_PB; ++k) acc[k] += Wl[(128 + i) * O_PB + k] * xv;
  }
#pragma unroll
  for (int k = 0; k < O_PB; ++k)
    g1[((size_t)b * C + o0 + k) * L + l] = acc[k];
  const int wv = threadIdx.x >> 6, lnn = threadIdx.x & 63;
#pragma unroll
  for (int k = 0; k < O_PB; ++k) {
    float v = acc[k];
    v += __shfl_xor(v, 1);  v += __shfl_xor(v, 2);  v += __shfl_xor(v, 4);
    v += __shfl_xor(v, 8);  v += __shfl_xor(v, 16); v += __shfl_xor(v, 32);
    if (lnn == 0) part[0][k][wv] = v;
    float q = acc[k] * acc[k];
    q += __shfl_xor(q, 1);  q += __shfl_xor(q, 2);  q += __shfl_xor(q, 4);
    q += __shfl_xor(q, 8);  q += __shfl_xor(q, 16); q += __shfl_xor(q, 32);
    if (lnn == 0) part[1][k][wv] = q;
  }
  __syncthreads();
  if (threadIdx.x < 2 * O_PB) {
    int which = threadIdx.x >= O_PB, k = threadIdx.x % O_PB;
    float v = part[which][k][0] + part[which][k][1] + part[which][k][2] + part[which][k][3];
    atomicAdd(&bnsum[which * 128 + o0 + k], v);
  }
}

// ---------- gate2: BN(from sums)+relu on loads; epilogue sigmoid + fuse (reads ycat) ----------
template <int O_PB>
__global__ void k_gate2_fuse(const float* __restrict__ g1,
                             const float* __restrict__ bnsum,
                             const float* __restrict__ bn_g, const float* __restrict__ bn_b,
                             const float* __restrict__ W, const float* __restrict__ bias,
                             const float* __restrict__ yu, const float* __restrict__ ycat,
                             float* __restrict__ fused) {
  __shared__ float Wl[O_PB * 128];
  __shared__ float sc[128], sh[128];
  const int o0 = blockIdx.y * O_PB;
  const int b  = blockIdx.z;
  for (int t = threadIdx.x; t < O_PB * 128; t += TPB) {
    int i = t / O_PB, k = t % O_PB;
    Wl[t] = W[(size_t)(o0 + k) * 128 + i];
  }
  for (int t = threadIdx.x; t < 128; t += TPB) {
    float sv = bnsum[t], qv = bnsum[128 + t];
    float mean = sv / (B_SZ * L);
    float var  = qv / (B_SZ * L) - mean * mean;
    float scv = bn_g[t] * rsqrtf(var + 1e-5f);
    sc[t] = scv;
    sh[t] = bn_b[t] - mean * scv;
  }
  __syncthreads();
  const int l = blockIdx.x * TPB + threadIdx.x;
  const float* Xb = g1 + (size_t)b * C * L + l;
  float acc[O_PB];
#pragma unroll
  for (int k = 0; k < O_PB; ++k) acc[k] = bias[o0 + k];
#pragma unroll 8
  for (int i = 0; i < 128; ++i) {
    float v = fmaxf(Xb[(size_t)i * L] * sc[i] + sh[i], 0.f);
#pragma unroll
    for (int k = 0; k < O_PB; ++k) acc[k] += Wl[i * O_PB + k] * v;
  }
#pragma unroll
  for (int k = 0; k < O_PB; ++k) {
    int o = o0 + k;
    float g = sigm(acc[k]);
    float yuv = yu[((size_t)b * C + o) * L + l];
    float cv = ycat[((size_t)b * C + o) * L + l];
    fused[((size_t)b * C + o) * L + l] = g * yuv + (1.f - g) * cv;
  }
}

// ---------- outproj: 1x1 conv over concat([fused, xr]) + atomic per-pixel LN stats ----------
template <int O_PB>
__global__ void k_outproj(const float* __restrict__ X1, const float* __restrict__ X2,
                          const float* __restrict__ W, const float* __restrict__ bias,
                          float* __restrict__ Y,
                          float* __restrict__ st3s, float* __restrict__ st3q) {
  __shared__ float Wl[O_PB * 256];
  const int o0 = blockIdx.y * O_PB;
  const int b  = blockIdx.z;
  for (int t = threadIdx.x; t < O_PB * 256; t += TPB) {
    int i = t / O_PB, k = t % O_PB;
    Wl[t] = W[(size_t)(o0 + k) * 256 + i];
  }
  __syncthreads();
  const int l = blockIdx.x * TPB + threadIdx.x;
  const float* Xb1 = X1 + (size_t)b * C * L + l;
  const float* Xb2 = X2 + (size_t)b * C * L + l;
  float acc[O_PB];
#pragma unroll
  for (int k = 0; k < O_PB; ++k) acc[k] = bias[o0 + k];
#pragma unroll 8
  for (int i = 0; i < 128; ++i) {
    float xv = Xb1[(size_t)i * L];
#pragma unroll
    for (int k = 0; k < O_PB; ++k) acc[k] += Wl[i * O_PB + k] * xv;
  }
#pragma unroll 8
  for (int i = 0; i < 128; ++i) {
    float xv = Xb2[(size_t)i * L];
#pragma unroll
    for (int k = 0; k < O_PB; ++k) acc[k] += Wl[(128 + i) * O_PB + k] * xv;
  }
  float ss = 0.f, qq = 0.f;
#pragma unroll
  for (int k = 0; k < O_PB; ++k) {
    Y[((size_t)b * C + o0 + k) * L + l] = acc[k];
    ss += acc[k]; qq += acc[k] * acc[k];
  }
  atomicAdd(&st3s[b * L + l], ss);
  atomicAdd(&st3q[b * L + l], qq);
}

// ---------- final channel LN from precomputed stats: fully-parallel float4 ----------
__global__ void k_ln_out(const float* __restrict__ X,
                         const float* __restrict__ st3s, const float* __restrict__ st3q,
                         const float* __restrict__ w, const float* __restrict__ bchan,
                         float* __restrict__ Y) {
  const int t  = blockIdx.x * TPB + threadIdx.x;   // float4 index
  const int gi = t * 4;
  const int l  = gi % L;
  const int c  = (gi / L) % C;
  const int b  = gi / (C * L);
  const float4 v  = ((const float4*)X)[t];
  const float4 s4 = *(const float4*)(st3s + b * L + l);
  const float4 q4 = *(const float4*)(st3q + b * L + l);
  const float wc = w[c], bc = bchan[c];
  float4 o;
  {
    float m = s4.x * (1.f / C);
    float r = rsqrtf(q4.x * (1.f / C) - m * m + 1e-6f);
    o.x = wc * (v.x - m) * r + bc;
  }
  {
    float m = s4.y * (1.f / C);
    float r = rsqrtf(q4.y * (1.f / C) - m * m + 1e-6f);
    o.y = wc * (v.y - m) * r + bc;
  }
  {
    float m = s4.z * (1.f / C);
    float r = rsqrtf(q4.z * (1.f / C) - m * m + 1e-6f);
    o.z = wc * (v.z - m) * r + bc;
  }
  {
    float m = s4.w * (1.f / C);
    float r = rsqrtf(q4.w * (1.f / C) - m * m + 1e-6f);
    o.w = wc * (v.w - m) * r + bc;
  }
  ((float4*)Y)[t] = o;
}

} // namespace

extern "C" void kernel_launch(void* const* d_in, const int* in_sizes, int n_in,
                              void* d_out, int out_size, void* d_ws, size_t ws_size,
                              hipStream_t stream) {
  const float* x         = (const float*)d_in[0];
  const float* ln_in_w   = (const float*)d_in[1];
  const float* ln_in_b   = (const float*)d_in[2];
  const float* inproj_w  = (const float*)d_in[3];
  const float* inproj_b  = (const float*)d_in[4];
  const float* ln_m_w    = (const float*)d_in[5];
  const float* ln_m_b    = (const float*)d_in[6];
  const float* convm_w   = (const float*)d_in[7];
  const float* convm_b   = (const float*)d_in[8];
  const float* convr_w   = (const float*)d_in[9];
  const float* convr_b   = (const float*)d_in[10];
  const float* ln_cat_w  = (const float*)d_in[11];
  const float* ln_cat_b  = (const float*)d_in[12];
  const float* xpf_w     = (const float*)d_in[13];
  const float* xpf_b     = (const float*)d_in[14];
  const float* dtf_w     = (const float*)d_in[15];
  const float* dtf_b     = (const float*)d_in[16];
  const float* Alog_f    = (const float*)d_in[17];
  const float* D_f       = (const float*)d_in[18];
  const float* xpb_w     = (const float*)d_in[19];
  const float* xpb_b     = (const float*)d_in[20];
  const float* dtb_w     = (const float*)d_in[21];
  const float* dtb_b     = (const float*)d_in[22];
  const float* Alog_b    = (const float*)d_in[23];
  const float* D_b       = (const float*)d_in[24];
  const float* xpu_w     = (const float*)d_in[25];
  const float* xpu_b     = (const float*)d_in[26];
  const float* dtu_w     = (const float*)d_in[27];
  const float* dtu_b     = (const float*)d_in[28];
  const float* Alog_u    = (const float*)d_in[29];
  const float* D_u       = (const float*)d_in[30];
  const float* gate1_w   = (const float*)d_in[31];
  const float* gate1_b   = (const float*)d_in[32];
  const float* bn_g      = (const float*)d_in[33];
  const float* bn_b      = (const float*)d_in[34];
  const float* gate2_w   = (const float*)d_in[35];
  const float* gate2_b   = (const float*)d_in[36];
  const float* outproj_w = (const float*)d_in[37];
  const float* outproj_b = (const float*)d_in[38];
  const float* outln_w   = (const float*)d_in[39];
  const float* outln_b   = (const float*)d_in[40];

  float* ws = (float*)d_ws;
  size_t off = 0;
  auto alloc = [&](size_t n) { float* p = ws + off; off += n; return p; };

  const size_t BL = (size_t)B_SZ * L;
  // zero-initialized region (one memset): st1s, st1q, st3s, st3q, rank, bnsum — contiguous
  float* st1s  = alloc(BL);
  float* st1q  = alloc(BL);
  float* st3s  = alloc(BL);
  float* st3q  = alloc(BL);
  int*   rank  = (int*)alloc(BL);
  float* bnsum = alloc(256);
  const size_t zeroBytes = (5 * BL + 256) * sizeof(float);

  float* xln   = alloc((size_t)B_SZ * C * L);
  float* xp    = alloc((size_t)B_SZ * 2 * C * L);
  float* xm    = alloc((size_t)B_SZ * C * L);
  float* xr    = alloc((size_t)B_SZ * C * L);
  float* unc   = alloc(BL);
  int*   idx   = (int*)alloc(BL);
  float* xs    = alloc((size_t)B_SZ * C * L);
  float* xdblF = alloc((size_t)4 * L * ROW);
  float* xdblU = alloc((size_t)2 * L * ROW);
  float* yf    = alloc((size_t)B_SZ * HALF * L);
  float* yb    = alloc((size_t)B_SZ * HALF * L);
  float* yu    = alloc((size_t)B_SZ * C * L);
  float* ycat  = alloc((size_t)B_SZ * C * L);
  float* g1    = alloc((size_t)B_SZ * C * L);
  float* fused = alloc((size_t)B_SZ * C * L);
  float* outp  = alloc((size_t)B_SZ * C * L);
  (void)ws_size; (void)in_sizes; (void)n_in; (void)out_size;

  const int pixB   = B_SZ * L / 64;        // 128 blocks (256 thr)
  const int pixB32 = B_SZ * L / 32;        // 256 blocks (256 thr, 32 px each)
  const int elemB  = B_SZ * C * L / TPB;   // 4096

  // 0) zero the accumulators — one small async fill
  hipMemsetAsync(st1s, 0, zeroBytes, stream);
  // 1) input pixel-LN, then pure inproj GEMM + st1 stats
  k_pixln<<<pixB32, TPB, 0, stream>>>(x, ln_in_w, ln_in_b, xln);
  k_conv_in<<<dim3(L / TPB, 32, B_SZ), TPB, 0, stream>>>(
      xln, inproj_w, inproj_b, xp, st1s, st1q);
  // 2) tiled dwconv (mamba LN from sums, res plain)
  k_dwconv_t<<<dim3(HH / 4, C, 2 * B_SZ), TPB, 0, stream>>>(
      xp, st1s, st1q, ln_m_w, ln_m_b, convm_w, convm_b, convr_w, convr_b, xm, xr);
  // 3) unc, rank-count, scatter-gather (byte-identical; preserves sort dice)
  k_unc<<<pixB, TPB, 0, stream>>>(xm, unc);
  k_rank<<<dim3(L / TPB, 8, B_SZ), TPB, 0, stream>>>(unc, rank);
  k_scatgath<<<elemB, TPB, 0, stream>>>(xm, rank, xs, idx);
  // 4) x-projections into padded ROW=48 layout; merged scan (B/C reg-prefetch)
  k_convx_all<<<dim3(L / TPB, 10, 6), TPB, 0, stream>>>(
      xm, xs, xpf_w, xpf_b, xpb_w, xpb_b, xpu_w, xpu_b, xdblF, xdblU);
  k_scan_all<<<512, 1024, 0, stream>>>(
      xdblF, xdblU, dtf_w, dtf_b, dtb_w, dtb_b, dtu_w, dtu_b,
      xm, xs, idx, Alog_f, Alog_b, Alog_u, D_f, D_b, D_u, yf, yb, yu);
  // 5) epilogue: cat-LN once, then three pure GEMMs (LDS weights), stats via atomics
  k_lncat<<<pixB32, TPB, 0, stream>>>(yf, yb, ln_cat_w, ln_cat_b, ycat);
  k_gate1<8><<<dim3(L / TPB, 16, B_SZ), TPB, 0, stream>>>(
      ycat, yu, gate1_w, gate1_b, g1, bnsum);
  k_gate2_fuse<8><<<dim3(L / TPB, 16, B_SZ), TPB, 0, stream>>>(
      g1, bnsum, bn_g, bn_b, gate2_w, gate2_b, yu, ycat, fused);
  k_outproj<8><<<dim3(L / TPB, 16, B_SZ), TPB, 0, stream>>>(
      fused, xr, outproj_w, outproj_b, outp, st3s, st3q);
  k_ln_out<<<(B_SZ * C * L / 4) / TPB, TPB, 0, stream>>>(
      outp, st3s, st3q, outln_w, outln_b, (float*)d_out);
}